// Round 3
// baseline (895.183 us; speedup 1.0000x reference)
//
#include <hip/hip_runtime.h>
#include <hip/hip_bf16.h>

// ---------- helpers ----------
__device__ __forceinline__ float lrelu(float x) { return x >= 0.f ? x : 0.01f * x; }
__device__ __forceinline__ void load8(const float* __restrict__ p, float* w) {
    float4 a = *(const float4*)p;
    float4 b = *(const float4*)(p + 4);
    w[0] = a.x; w[1] = a.y; w[2] = a.z; w[3] = a.w;
    w[4] = b.x; w[5] = b.y; w[6] = b.z; w[7] = b.w;
}

// ---------- shared MLP tail: layers 1..4 + softmax over 16 positions ----------
// All 256 threads must call (contains __syncthreads).
__device__ void tail_layers(int t,
    const float (*h0)[16], float (*h1)[16], float (*h2)[16], float (*h3)[16],
    float* wn,
    const float* __restrict__ w1, const float* __restrict__ w2,
    const float* __restrict__ w3, const float* __restrict__ w4)
{
    // layer 1: 128 oc x 16 pos, in 256
    {
        int oc = t & 127, g = t >> 7;               // g in {0,1} -> 8 positions each
        float acc[8];
#pragma unroll
        for (int p = 0; p < 8; ++p) acc[p] = 0.f;
        const float* wr = w1 + oc * 256;
        for (int c0 = 0; c0 < 256; c0 += 8) {
            float w[8]; load8(wr + c0, w);
#pragma unroll
            for (int k = 0; k < 8; ++k) {
                const float* hp = h0[c0 + k] + g * 8;
#pragma unroll
                for (int p = 0; p < 8; ++p) acc[p] += w[k] * hp[p];
            }
        }
#pragma unroll
        for (int p = 0; p < 8; ++p) h1[oc][g * 8 + p] = lrelu(acc[p]);
    }
    __syncthreads();
    // layer 2: 64 oc x 16 pos, in 128
    {
        int oc = t & 63, g = t >> 6;                // g in {0..3} -> 4 positions
        float acc[4] = {0.f, 0.f, 0.f, 0.f};
        const float* wr = w2 + oc * 128;
        for (int c0 = 0; c0 < 128; c0 += 8) {
            float w[8]; load8(wr + c0, w);
#pragma unroll
            for (int k = 0; k < 8; ++k) {
                const float* hp = h1[c0 + k] + g * 4;
#pragma unroll
                for (int p = 0; p < 4; ++p) acc[p] += w[k] * hp[p];
            }
        }
#pragma unroll
        for (int p = 0; p < 4; ++p) h2[oc][g * 4 + p] = lrelu(acc[p]);
    }
    __syncthreads();
    // layer 3: 32 oc x 16 pos, in 64
    {
        int oc = t & 31, g = t >> 5;                // g in {0..7} -> 2 positions
        float acc[2] = {0.f, 0.f};
        const float* wr = w3 + oc * 64;
        for (int c0 = 0; c0 < 64; c0 += 8) {
            float w[8]; load8(wr + c0, w);
#pragma unroll
            for (int k = 0; k < 8; ++k) {
#pragma unroll
                for (int p = 0; p < 2; ++p) acc[p] += w[k] * h2[c0 + k][g * 2 + p];
            }
        }
#pragma unroll
        for (int p = 0; p < 2; ++p) h3[oc][g * 2 + p] = lrelu(acc[p]);
    }
    __syncthreads();
    // layer 4: 16 scores (no activation)
    if (t < 16) {
        float s = 0.f;
#pragma unroll
        for (int c = 0; c < 32; ++c) s += w4[c] * h3[c][t];
        wn[t] = s;
    }
    __syncthreads();
    // softmax over 16 (trivial, single thread)
    if (t == 0) {
        float m = wn[0];
#pragma unroll
        for (int p = 1; p < 16; ++p) m = fmaxf(m, wn[p]);
        float e[16], sum = 0.f;
#pragma unroll
        for (int p = 0; p < 16; ++p) { e[p] = __expf(wn[p] - m); sum += e[p]; }
        float inv = 1.f / sum;
#pragma unroll
        for (int p = 0; p < 16; ++p) wn[p] = e[p] * inv;
    }
    __syncthreads();
}

// ---------- kernel A: template branch (32 problems) ----------
__global__ __launch_bounds__(256) void templ_kernel(
    const float* __restrict__ tf,
    const float* __restrict__ w0, const float* __restrict__ w1,
    const float* __restrict__ w2, const float* __restrict__ w3,
    const float* __restrict__ w4, float* __restrict__ out)
{
    __shared__ float patch[256][16];
    __shared__ float mean_[256];
    __shared__ float h0[256][16];
    __shared__ float h1[128][16];
    __shared__ float h2[64][16];
    __shared__ float h3[32][16];
    __shared__ float wn[16];
    int b = blockIdx.x, t = threadIdx.x;

    const float* src = tf + (size_t)(b * 256 + t) * 16;   // 64B aligned
    float s = 0.f;
#pragma unroll
    for (int q = 0; q < 4; ++q) {
        float4 v = ((const float4*)src)[q];
        patch[t][q * 4 + 0] = v.x; patch[t][q * 4 + 1] = v.y;
        patch[t][q * 4 + 2] = v.z; patch[t][q * 4 + 3] = v.w;
        s += v.x + v.y + v.z + v.w;
    }
    mean_[t] = s * (1.f / 16.f);
    __syncthreads();

    // layer 0: oc = t; in = [mean(256); pixel(256)]
    {
        const float* wr = w0 + (size_t)t * 512;
        float accm = 0.f;
        for (int c0 = 0; c0 < 256; c0 += 8) {
            float w[8]; load8(wr + c0, w);
#pragma unroll
            for (int k = 0; k < 8; ++k) accm += w[k] * mean_[c0 + k];
        }
        float acc[16];
#pragma unroll
        for (int p = 0; p < 16; ++p) acc[p] = accm;
        for (int c0 = 0; c0 < 256; c0 += 8) {
            float w[8]; load8(wr + 256 + c0, w);
#pragma unroll
            for (int k = 0; k < 8; ++k) {
                const float* hp = patch[c0 + k];
#pragma unroll
                for (int p = 0; p < 16; ++p) acc[p] += w[k] * hp[p];
            }
        }
#pragma unroll
        for (int p = 0; p < 16; ++p) h0[t][p] = lrelu(acc[p]);
    }
    __syncthreads();

    tail_layers(t, h0, h1, h2, h3, wn, w1, w2, w3, w4);

    float acc = 0.f;
#pragma unroll
    for (int p = 0; p < 16; ++p) acc += patch[t][p] * wn[p];
    out[b * 272 + t] = acc;
    if (t < 16) out[b * 272 + 256 + t] = wn[t];
}

// ---------- kernel B: A0[b,u,v,oc] = w0[:,256:512] @ cand[b,:,u,v] ----------
__global__ __launch_bounds__(256) void a0_kernel(
    const float* __restrict__ cand,
    const float* __restrict__ w0, float* __restrict__ A0)
{
    __shared__ float row[256][20];
    int b = blockIdx.x / 20, u = blockIdx.x % 20;
    int t = threadIdx.x;
    const float* src = cand + (size_t)(b * 256 + t) * 400 + u * 20; // 80B aligned
#pragma unroll
    for (int q = 0; q < 5; ++q) {
        float4 v = ((const float4*)src)[q];
        row[t][q * 4 + 0] = v.x; row[t][q * 4 + 1] = v.y;
        row[t][q * 4 + 2] = v.z; row[t][q * 4 + 3] = v.w;
    }
    __syncthreads();

    float acc[20];
#pragma unroll
    for (int v = 0; v < 20; ++v) acc[v] = 0.f;
    const float* wr = w0 + (size_t)t * 512 + 256;
    for (int c0 = 0; c0 < 256; c0 += 8) {
        float w[8]; load8(wr + c0, w);
#pragma unroll
        for (int k = 0; k < 8; ++k) {
            const float* rp = row[c0 + k];
#pragma unroll
            for (int v = 0; v < 20; ++v) acc[v] += w[k] * rp[v];
        }
    }
    float* dst = A0 + (size_t)((b * 20 + u) * 20) * 256 + t;
#pragma unroll
    for (int v = 0; v < 20; ++v) dst[(size_t)v * 256] = acc[v];
}

// ---------- kernel C: per-patch candidate problems (32*17*17 blocks) ----------
__global__ __launch_bounds__(256) void cand_kernel(
    const float* __restrict__ cand,
    const float* __restrict__ w0, const float* __restrict__ w1,
    const float* __restrict__ w2, const float* __restrict__ w3,
    const float* __restrict__ w4,
    const float* __restrict__ A0, float* __restrict__ out)
{
    __shared__ float patch[256][16];
    __shared__ float mean_[256];
    __shared__ float h0[256][16];
    __shared__ float h1[128][16];
    __shared__ float h2[64][16];
    __shared__ float h3[32][16];
    __shared__ float wn[16];

    int blk = blockIdx.x;
    int b = blk / 289, r = blk % 289, y = r / 17, x = r % 17;
    int t = threadIdx.x;

    // load 4x4 patch for channel t, compute mean
    const float* src = cand + (size_t)(b * 256 + t) * 400 + y * 20 + x;
    float s = 0.f;
#pragma unroll
    for (int i = 0; i < 4; ++i)
#pragma unroll
        for (int j = 0; j < 4; ++j) {
            float v = src[i * 20 + j];
            patch[t][i * 4 + j] = v; s += v;
        }
    mean_[t] = s * (1.f / 16.f);
    __syncthreads();

    // layer 0: mean path per problem + precomputed pixel path from A0
    {
        const float* wr = w0 + (size_t)t * 512;
        float accm = 0.f;
        for (int c0 = 0; c0 < 256; c0 += 8) {
            float w[8]; load8(wr + c0, w);
#pragma unroll
            for (int k = 0; k < 8; ++k) accm += w[k] * mean_[c0 + k];
        }
        const float* a0p = A0 + (size_t)((b * 20 + y) * 20 + x) * 256 + t;
#pragma unroll
        for (int i = 0; i < 4; ++i)
#pragma unroll
            for (int j = 0; j < 4; ++j)
                h0[t][i * 4 + j] = lrelu(accm + a0p[(size_t)(i * 20 + j) * 256]);
    }
    __syncthreads();

    tail_layers(t, h0, h1, h2, h3, wn, w1, w2, w3, w4);

    float acc = 0.f;
#pragma unroll
    for (int p = 0; p < 16; ++p) acc += patch[t][p] * wn[p];
    out[8704 + (size_t)(b * 256 + t) * 289 + y * 17 + x] = acc;
}

// ---------- launch ----------
extern "C" void kernel_launch(void* const* d_in, const int* in_sizes, int n_in,
                              void* d_out, int out_size, void* d_ws, size_t ws_size,
                              hipStream_t stream)
{
    const float* tf = (const float*)d_in[0];
    const float* cf = (const float*)d_in[1];
    const float* w0 = (const float*)d_in[2];
    const float* w1 = (const float*)d_in[3];
    const float* w2 = (const float*)d_in[4];
    const float* w3 = (const float*)d_in[5];
    const float* w4 = (const float*)d_in[6];
    float* out = (float*)d_out;
    float* A0 = (float*)d_ws;   // 32*400*256 fp32 = 13.1 MB scratch

    a0_kernel<<<32 * 20, 256, 0, stream>>>(cf, w0, A0);
    templ_kernel<<<32, 256, 0, stream>>>(tf, w0, w1, w2, w3, w4, out);
    cand_kernel<<<32 * 289, 256, 0, stream>>>(cf, w0, w1, w2, w3, w4, A0, out);
}

// Round 5
// 241.368 us; speedup vs baseline: 3.7088x; 3.7088x over previous
//
#include <hip/hip_runtime.h>
#include <hip/hip_bf16.h>

typedef __attribute__((ext_vector_type(8))) short short8v;   // 8 bf16 = 4 VGPR
typedef __attribute__((ext_vector_type(4))) float f32x4;

// ---------- packed weights (written by prep_kernel every launch) ----------
__device__ __align__(16) float g_w0T[256 * 512];                       // fp32 [c][j] j<256 mean-w, j>=256 pixel-w
__device__ __align__(16) unsigned short g_wp1h[8 * 8 * 64 * 8], g_wp1l[8 * 8 * 64 * 8]; // L1 A-frags hi/lo
__device__ __align__(16) unsigned short g_wp2h[4 * 4 * 64 * 8], g_wp2l[4 * 4 * 64 * 8]; // L2
__device__ __align__(16) unsigned short g_wp3h[2 * 2 * 64 * 8], g_wp3l[2 * 2 * 64 * 8]; // L3

// ---------- helpers ----------
__device__ __forceinline__ float lrelu(float x) { return x >= 0.f ? x : 0.01f * x; }
__device__ __forceinline__ unsigned short f2us(float x) {
    __hip_bfloat16 h = __float2bfloat16(x);
    return *(unsigned short*)&h;
}
__device__ __forceinline__ float us2f(unsigned short u) {
    union { unsigned i; float f; } c; c.i = ((unsigned)u) << 16; return c.f;
}
__device__ __forceinline__ void split_bf(float v, unsigned short& hi, unsigned short& lo) {
    hi = f2us(v); lo = f2us(v - us2f(hi));
}
// lrelu + hi/lo split + pack a f32x4 accumulator quad into two uint2 (4 bf16 each)
__device__ __forceinline__ void pack_hilo(const f32x4& a, uint2& ph, uint2& pl) {
    unsigned short h[4], lo[4];
#pragma unroll
    for (int i = 0; i < 4; ++i) {
        float v = lrelu(a[i]);
        h[i] = f2us(v); lo[i] = f2us(v - us2f(h[i]));
    }
    ph.x = (unsigned)h[0] | ((unsigned)h[1] << 16);
    ph.y = (unsigned)h[2] | ((unsigned)h[3] << 16);
    pl.x = (unsigned)lo[0] | ((unsigned)lo[1] << 16);
    pl.y = (unsigned)lo[2] | ((unsigned)lo[3] << 16);
}

// ---------- prep: transpose w0 (fp32), pack w1..w3 into hi/lo MFMA A-frags ----------
__global__ __launch_bounds__(256) void prep_kernel(
    const float* __restrict__ w0, const float* __restrict__ w1,
    const float* __restrict__ w2, const float* __restrict__ w3)
{
    int id = blockIdx.x * 256 + threadIdx.x;
    int stride = gridDim.x * 256;
    for (int i = id; i < 256 * 512; i += stride) {        // w0T[c][j] fp32
        int c = i >> 9, j = i & 511;
        g_w0T[i] = (j < 256) ? w0[j * 512 + c] : w0[(j - 256) * 512 + 256 + c];
    }
    // A-frag: lane l holds A[row = l&15][k = (l>>4)*8 + e]
    for (int i = id; i < 8 * 8 * 64 * 8; i += stride) {   // L1: 128x256
        int e = i & 7, l = (i >> 3) & 63, k0 = (i >> 9) & 7, m = i >> 12;
        int oc = m * 16 + (l & 15), c = k0 * 32 + ((l >> 4) * 8) + e;
        unsigned short hi, lo; split_bf(w1[oc * 256 + c], hi, lo);
        g_wp1h[i] = hi; g_wp1l[i] = lo;
    }
    for (int i = id; i < 4 * 4 * 64 * 8; i += stride) {   // L2: 64x128
        int e = i & 7, l = (i >> 3) & 63, k0 = (i >> 9) & 3, m = i >> 11;
        int oc = m * 16 + (l & 15), c = k0 * 32 + ((l >> 4) * 8) + e;
        unsigned short hi, lo; split_bf(w2[oc * 128 + c], hi, lo);
        g_wp2h[i] = hi; g_wp2l[i] = lo;
    }
    for (int i = id; i < 2 * 2 * 64 * 8; i += stride) {   // L3: 32x64
        int e = i & 7, l = (i >> 3) & 63, k0 = (i >> 9) & 1, m = i >> 10;
        int oc = m * 16 + (l & 15), c = k0 * 32 + ((l >> 4) * 8) + e;
        unsigned short hi, lo; split_bf(w3[oc * 64 + c], hi, lo);
        g_wp3h[i] = hi; g_wp3l[i] = lo;
    }
}

// ---------- a0: A0[b,pix,oc] = w0_pixel @ cand[b,:,pix]  (fp32) ----------
__global__ __launch_bounds__(256) void a0_kernel(
    const float* __restrict__ cand, float* __restrict__ A0)
{
    __shared__ float row[256][20];
    int b = blockIdx.x / 20, u = blockIdx.x % 20;
    int t = threadIdx.x;
    const float* src = cand + (size_t)(b * 256 + t) * 400 + u * 20; // 80B aligned
#pragma unroll
    for (int q = 0; q < 5; ++q) {
        float4 v = ((const float4*)src)[q];
        row[t][q * 4 + 0] = v.x; row[t][q * 4 + 1] = v.y;
        row[t][q * 4 + 2] = v.z; row[t][q * 4 + 3] = v.w;
    }
    __syncthreads();
    float acc[20];
#pragma unroll
    for (int v = 0; v < 20; ++v) acc[v] = 0.f;
    for (int c = 0; c < 256; ++c) {
        float wv = g_w0T[c * 512 + 256 + t];   // lane-coalesced
        const float* rp = row[c];
#pragma unroll
        for (int v = 0; v < 20; ++v) acc[v] += wv * rp[v];
    }
    float* dst = A0 + (size_t)(b * 400 + u * 20) * 256 + t;
#pragma unroll
    for (int v = 0; v < 20; ++v) dst[(size_t)v * 256] = acc[v];
}

// ---------- main: blocks 0..31 = template, 32..9279 = candidate patches ----------
// LDS (bytes): h0hi[16p][256c] bf16 swz @0 (8K) | h0lo @8192 (8K)
//   h1hi @16384 (4K) | h1lo @20480 (4K) | h2hi @24576 (2K) | h2lo @26624 (2K)
//   h3 f32 @28672 (2K) | wn @30720
//   phase-1 overlays (dead until h1 written): mean @16384 (1K); template patchL @17408 (16K)
__global__ __launch_bounds__(256) void main_kernel(
    const float* __restrict__ tf, const float* __restrict__ cand,
    const float* __restrict__ w4, const float* __restrict__ A0,
    float* __restrict__ out)
{
    __shared__ __align__(16) char smem[33792];
    const int OFF_H0HI = 0, OFF_H0LO = 8192;
    const int OFF_H1HI = 16384, OFF_H1LO = 20480;
    const int OFF_H2HI = 24576, OFF_H2LO = 26624;
    const int OFF_H3 = 28672, OFF_WN = 30720;

    int blk = blockIdx.x, t = threadIdx.x;
    int l = t & 63, w = t >> 6;
    bool is_tpl = blk < 32;
    float patch[16];
    int b, r = 0;

    if (!is_tpl) {
        int idx = blk - 32;
        b = idx / 289; r = idx % 289;
        int y = r / 17, x = r % 17;
        const float* csrc = cand + (size_t)(b * 256 + t) * 400 + y * 20 + x;
        float s = 0.f;
#pragma unroll
        for (int p = 0; p < 16; ++p) { patch[p] = csrc[(p >> 2) * 20 + (p & 3)]; s += patch[p]; }
        float* mean_ = (float*)(smem + OFF_H1HI);
        mean_[t] = s * (1.f / 16.f);
        __syncthreads();
        float m0 = 0.f;
        for (int c = 0; c < 256; ++c) m0 += g_w0T[c * 512 + t] * mean_[c];
        const float* a0p = A0 + (size_t)(b * 400 + y * 20 + x) * 256 + t;
#pragma unroll
        for (int p = 0; p < 16; ++p) {
            float h = lrelu(m0 + a0p[(size_t)((p >> 2) * 20 + (p & 3)) * 256]);
            unsigned short hi, lo; split_bf(h, hi, lo);
            int byte = p * 512 + ((((t >> 3) ^ (p & 7)) << 4)) + (t & 7) * 2;
            *(unsigned short*)(smem + OFF_H0HI + byte) = hi;
            *(unsigned short*)(smem + OFF_H0LO + byte) = lo;
        }
    } else {
        b = blk;
        float* meanp = (float*)(smem + OFF_H1HI);
        float (*patchL)[16] = (float(*)[16])(smem + OFF_H1HI + 1024);
        const float* src = tf + (size_t)(b * 256 + t) * 16;
        float s = 0.f;
#pragma unroll
        for (int p = 0; p < 16; ++p) {
            float v = src[p];
            patch[p] = v; patchL[t][p] = v; s += v;
        }
        meanp[t] = s * (1.f / 16.f);
        __syncthreads();
        float m0 = 0.f, accp[16];
#pragma unroll
        for (int p = 0; p < 16; ++p) accp[p] = 0.f;
        for (int c = 0; c < 256; ++c) {
            float wm = g_w0T[c * 512 + t];
            float wp = g_w0T[c * 512 + 256 + t];
            m0 += wm * meanp[c];
            const float* pr = patchL[c];
#pragma unroll
            for (int p = 0; p < 16; ++p) accp[p] += wp * pr[p];
        }
#pragma unroll
        for (int p = 0; p < 16; ++p) {
            float h = lrelu(m0 + accp[p]);
            unsigned short hi, lo; split_bf(h, hi, lo);
            int byte = p * 512 + ((((t >> 3) ^ (p & 7)) << 4)) + (t & 7) * 2;
            *(unsigned short*)(smem + OFF_H0HI + byte) = hi;
            *(unsigned short*)(smem + OFF_H0LO + byte) = lo;
        }
    }
    __syncthreads();

    int p_ = l & 15, q = l >> 4;

    // ---- layer 1: [128x256]x[256x16]; wave w owns M-tiles 2w,2w+1; 3-MFMA hi/lo ----
    {
        f32x4 acc0 = {0.f, 0.f, 0.f, 0.f}, acc1 = {0.f, 0.f, 0.f, 0.f};
        const short8v* A1h = (const short8v*)g_wp1h;
        const short8v* A1l = (const short8v*)g_wp1l;
#pragma unroll
        for (int k0 = 0; k0 < 8; ++k0) {
            int off = p_ * 512 + ((((k0 * 4 + q) ^ (p_ & 7)) << 4));
            short8v bh = *(const short8v*)(smem + OFF_H0HI + off);
            short8v bl = *(const short8v*)(smem + OFF_H0LO + off);
            short8v ah0 = A1h[((2 * w) * 8 + k0) * 64 + l];
            short8v al0 = A1l[((2 * w) * 8 + k0) * 64 + l];
            short8v ah1 = A1h[((2 * w + 1) * 8 + k0) * 64 + l];
            short8v al1 = A1l[((2 * w + 1) * 8 + k0) * 64 + l];
            acc0 = __builtin_amdgcn_mfma_f32_16x16x32_bf16(ah0, bh, acc0, 0, 0, 0);
            acc0 = __builtin_amdgcn_mfma_f32_16x16x32_bf16(ah0, bl, acc0, 0, 0, 0);
            acc0 = __builtin_amdgcn_mfma_f32_16x16x32_bf16(al0, bh, acc0, 0, 0, 0);
            acc1 = __builtin_amdgcn_mfma_f32_16x16x32_bf16(ah1, bh, acc1, 0, 0, 0);
            acc1 = __builtin_amdgcn_mfma_f32_16x16x32_bf16(ah1, bl, acc1, 0, 0, 0);
            acc1 = __builtin_amdgcn_mfma_f32_16x16x32_bf16(al1, bh, acc1, 0, 0, 0);
        }
        int gr0 = 2 * (2 * w) + (q >> 1), gr1 = 2 * (2 * w + 1) + (q >> 1);
        uint2 ph0, pl0, ph1, pl1;
        pack_hilo(acc0, ph0, pl0);
        pack_hilo(acc1, ph1, pl1);
        int e0 = p_ * 256 + ((gr0 ^ (p_ & 7)) << 4) + (q & 1) * 8;
        int e1 = p_ * 256 + ((gr1 ^ (p_ & 7)) << 4) + (q & 1) * 8;
        *(uint2*)(smem + OFF_H1HI + e0) = ph0;
        *(uint2*)(smem + OFF_H1LO + e0) = pl0;
        *(uint2*)(smem + OFF_H1HI + e1) = ph1;
        *(uint2*)(smem + OFF_H1LO + e1) = pl1;
    }
    __syncthreads();

    // ---- layer 2: [64x128]x[128x16]; wave w owns M-tile w ----
    {
        f32x4 acc = {0.f, 0.f, 0.f, 0.f};
        const short8v* A2h = (const short8v*)g_wp2h;
        const short8v* A2l = (const short8v*)g_wp2l;
#pragma unroll
        for (int k0 = 0; k0 < 4; ++k0) {
            int off = p_ * 256 + ((((k0 * 4 + q) ^ (p_ & 7)) << 4));
            short8v bh = *(const short8v*)(smem + OFF_H1HI + off);
            short8v bl = *(const short8v*)(smem + OFF_H1LO + off);
            short8v ah = A2h[(w * 4 + k0) * 64 + l];
            short8v al = A2l[(w * 4 + k0) * 64 + l];
            acc = __builtin_amdgcn_mfma_f32_16x16x32_bf16(ah, bh, acc, 0, 0, 0);
            acc = __builtin_amdgcn_mfma_f32_16x16x32_bf16(ah, bl, acc, 0, 0, 0);
            acc = __builtin_amdgcn_mfma_f32_16x16x32_bf16(al, bh, acc, 0, 0, 0);
        }
        int gr = 2 * w + (q >> 1);
        uint2 ph, pl;
        pack_hilo(acc, ph, pl);
        int e = p_ * 128 + ((gr ^ (p_ & 7)) << 4) + (q & 1) * 8;
        *(uint2*)(smem + OFF_H2HI + e) = ph;
        *(uint2*)(smem + OFF_H2LO + e) = pl;
    }
    __syncthreads();

    // ---- layer 3: [32x64]x[64x16]; waves 0,1; h3 stored fp32 ----
    if (w < 2) {
        f32x4 acc = {0.f, 0.f, 0.f, 0.f};
        const short8v* A3h = (const short8v*)g_wp3h;
        const short8v* A3l = (const short8v*)g_wp3l;
#pragma unroll
        for (int k0 = 0; k0 < 2; ++k0) {
            int off = p_ * 128 + ((((k0 * 4 + q) ^ (p_ & 7)) << 4));
            short8v bh = *(const short8v*)(smem + OFF_H2HI + off);
            short8v bl = *(const short8v*)(smem + OFF_H2LO + off);
            short8v ah = A3h[(w * 2 + k0) * 64 + l];
            short8v al = A3l[(w * 2 + k0) * 64 + l];
            acc = __builtin_amdgcn_mfma_f32_16x16x32_bf16(ah, bh, acc, 0, 0, 0);
            acc = __builtin_amdgcn_mfma_f32_16x16x32_bf16(ah, bl, acc, 0, 0, 0);
            acc = __builtin_amdgcn_mfma_f32_16x16x32_bf16(al, bh, acc, 0, 0, 0);
        }
#pragma unroll
        for (int rg = 0; rg < 4; ++rg) {
            float v = lrelu(acc[rg]);
            int oc = w * 16 + q * 4 + rg;
            *(float*)(smem + OFF_H3 + p_ * 128 + ((oc ^ (p_ & 7)) << 2)) = v;
        }
    }
    __syncthreads();

    // ---- layer 4 + softmax ----
    float* wn = (float*)(smem + OFF_WN);
    if (t < 16) {
        float s = 0.f;
#pragma unroll
        for (int c = 0; c < 32; ++c)
            s += w4[c] * *(const float*)(smem + OFF_H3 + t * 128 + ((c ^ (t & 7)) << 2));
        wn[t] = s;
    }
    __syncthreads();
    if (t == 0) {
        float m = wn[0];
#pragma unroll
        for (int p = 1; p < 16; ++p) m = fmaxf(m, wn[p]);
        float e[16], sum = 0.f;
#pragma unroll
        for (int p = 0; p < 16; ++p) { e[p] = __expf(wn[p] - m); sum += e[p]; }
        float inv = 1.f / sum;
#pragma unroll
        for (int p = 0; p < 16; ++p) wn[p] = e[p] * inv;
    }
    __syncthreads();

    // ---- weighted pooling + store ----
    float accv = 0.f;
#pragma unroll
    for (int p = 0; p < 16; ++p) accv += patch[p] * wn[p];
    if (is_tpl) {
        out[b * 272 + t] = accv;
        if (t < 16) out[b * 272 + 256 + t] = wn[t];
    } else {
        out[8704 + (size_t)(b * 256 + t) * 289 + r] = accv;
    }
}

// ---------- launch ----------
extern "C" void kernel_launch(void* const* d_in, const int* in_sizes, int n_in,
                              void* d_out, int out_size, void* d_ws, size_t ws_size,
                              hipStream_t stream)
{
    const float* tf = (const float*)d_in[0];
    const float* cf = (const float*)d_in[1];
    const float* w0 = (const float*)d_in[2];
    const float* w1 = (const float*)d_in[3];
    const float* w2 = (const float*)d_in[4];
    const float* w3 = (const float*)d_in[5];
    const float* w4 = (const float*)d_in[6];
    float* out = (float*)d_out;
    float* A0 = (float*)d_ws;   // 32*400*256 fp32 = 13.1 MB (fits: proven round 3)

    prep_kernel<<<680, 256, 0, stream>>>(w0, w1, w2, w3);
    a0_kernel<<<32 * 20, 256, 0, stream>>>(cf, A0);
    main_kernel<<<32 + 32 * 289, 256, 0, stream>>>(tf, cf, w4, A0, out);
}

// Round 6
// 176.402 us; speedup vs baseline: 5.0747x; 1.3683x over previous
//
#include <hip/hip_runtime.h>
#include <hip/hip_bf16.h>

typedef __attribute__((ext_vector_type(8))) short short8v;   // 8 bf16 = 4 VGPR
typedef __attribute__((ext_vector_type(4))) float f32x4;

// ---------- packed weights (written by prep_kernel every launch) ----------
__device__ __align__(16) float g_w0T[256 * 512];                       // fp32 [c][j] j<256 mean-w, j>=256 pixel-w
__device__ __align__(16) unsigned short g_wp1h[8 * 8 * 64 * 8], g_wp1l[8 * 8 * 64 * 8]; // L1 A-frags hi/lo
__device__ __align__(16) unsigned short g_wp2h[4 * 4 * 64 * 8], g_wp2l[4 * 4 * 64 * 8]; // L2
__device__ __align__(16) unsigned short g_wp3h[2 * 2 * 64 * 8], g_wp3l[2 * 2 * 64 * 8]; // L3

// ---------- helpers ----------
__device__ __forceinline__ float lrelu(float x) { return x >= 0.f ? x : 0.01f * x; }
__device__ __forceinline__ unsigned short f2us(float x) {
    __hip_bfloat16 h = __float2bfloat16(x);
    return *(unsigned short*)&h;
}
__device__ __forceinline__ float us2f(unsigned short u) {
    union { unsigned i; float f; } c; c.i = ((unsigned)u) << 16; return c.f;
}
__device__ __forceinline__ void split_bf(float v, unsigned short& hi, unsigned short& lo) {
    hi = f2us(v); lo = f2us(v - us2f(hi));
}
__device__ __forceinline__ void pack_hilo(const f32x4& a, uint2& ph, uint2& pl) {
    unsigned short h[4], lo[4];
#pragma unroll
    for (int i = 0; i < 4; ++i) {
        float v = lrelu(a[i]);
        h[i] = f2us(v); lo[i] = f2us(v - us2f(h[i]));
    }
    ph.x = (unsigned)h[0] | ((unsigned)h[1] << 16);
    ph.y = (unsigned)h[2] | ((unsigned)h[3] << 16);
    pl.x = (unsigned)lo[0] | ((unsigned)lo[1] << 16);
    pl.y = (unsigned)lo[2] | ((unsigned)lo[3] << 16);
}

// ---------- prep: transpose w0 (fp32), pack w1..w3 into hi/lo MFMA A-frags ----------
__global__ __launch_bounds__(256) void prep_kernel(
    const float* __restrict__ w0, const float* __restrict__ w1,
    const float* __restrict__ w2, const float* __restrict__ w3)
{
    int id = blockIdx.x * 256 + threadIdx.x;
    int stride = gridDim.x * 256;
    for (int i = id; i < 256 * 512; i += stride) {        // w0T[c][j] fp32
        int c = i >> 9, j = i & 511;
        g_w0T[i] = (j < 256) ? w0[j * 512 + c] : w0[(j - 256) * 512 + 256 + c];
    }
    // A-frag: lane l holds A[row = l&15][k = (l>>4)*8 + e]
    for (int i = id; i < 8 * 8 * 64 * 8; i += stride) {   // L1: 128x256
        int e = i & 7, l = (i >> 3) & 63, k0 = (i >> 9) & 7, m = i >> 12;
        int oc = m * 16 + (l & 15), c = k0 * 32 + ((l >> 4) * 8) + e;
        unsigned short hi, lo; split_bf(w1[oc * 256 + c], hi, lo);
        g_wp1h[i] = hi; g_wp1l[i] = lo;
    }
    for (int i = id; i < 4 * 4 * 64 * 8; i += stride) {   // L2: 64x128
        int e = i & 7, l = (i >> 3) & 63, k0 = (i >> 9) & 3, m = i >> 11;
        int oc = m * 16 + (l & 15), c = k0 * 32 + ((l >> 4) * 8) + e;
        unsigned short hi, lo; split_bf(w2[oc * 128 + c], hi, lo);
        g_wp2h[i] = hi; g_wp2l[i] = lo;
    }
    for (int i = id; i < 2 * 2 * 64 * 8; i += stride) {   // L3: 32x64
        int e = i & 7, l = (i >> 3) & 63, k0 = (i >> 9) & 1, m = i >> 10;
        int oc = m * 16 + (l & 15), c = k0 * 32 + ((l >> 4) * 8) + e;
        unsigned short hi, lo; split_bf(w3[oc * 64 + c], hi, lo);
        g_wp3h[i] = hi; g_wp3l[i] = lo;
    }
}

// ---------- a0 wide: A0f[b,pix,j] = w0T[:,j] @ cand[b,:,pix], j in [0,512) fp32 ----------
__global__ __launch_bounds__(512) void a0_wide_kernel(
    const float* __restrict__ cand, float* __restrict__ A0f)
{
    __shared__ float row[256][20];
    int b = blockIdx.x / 20, u = blockIdx.x % 20;
    int t = threadIdx.x;
    if (t < 256) {
        const float* src = cand + (size_t)(b * 256 + t) * 400 + u * 20;
#pragma unroll
        for (int q = 0; q < 5; ++q) {
            float4 v = ((const float4*)src)[q];
            row[t][q * 4 + 0] = v.x; row[t][q * 4 + 1] = v.y;
            row[t][q * 4 + 2] = v.z; row[t][q * 4 + 3] = v.w;
        }
    }
    __syncthreads();
    float acc[20];
#pragma unroll
    for (int v = 0; v < 20; ++v) acc[v] = 0.f;
    for (int c = 0; c < 256; ++c) {
        float wv = g_w0T[c * 512 + t];        // lane-coalesced over t (both halves)
        const float* rp = row[c];
#pragma unroll
        for (int v = 0; v < 20; ++v) acc[v] += wv * rp[v];
    }
    float* dst = A0f + (size_t)(b * 400 + u * 20) * 512 + t;
#pragma unroll
    for (int v = 0; v < 20; ++v) dst[(size_t)v * 512] = acc[v];
}

// ---------- a0 narrow (fallback, pixel half only): A0[b,pix,oc] fp32 ----------
__global__ __launch_bounds__(256) void a0_narrow_kernel(
    const float* __restrict__ cand, float* __restrict__ A0)
{
    __shared__ float row[256][20];
    int b = blockIdx.x / 20, u = blockIdx.x % 20;
    int t = threadIdx.x;
    const float* src = cand + (size_t)(b * 256 + t) * 400 + u * 20;
#pragma unroll
    for (int q = 0; q < 5; ++q) {
        float4 v = ((const float4*)src)[q];
        row[t][q * 4 + 0] = v.x; row[t][q * 4 + 1] = v.y;
        row[t][q * 4 + 2] = v.z; row[t][q * 4 + 3] = v.w;
    }
    __syncthreads();
    float acc[20];
#pragma unroll
    for (int v = 0; v < 20; ++v) acc[v] = 0.f;
    for (int c = 0; c < 256; ++c) {
        float wv = g_w0T[c * 512 + 256 + t];
        const float* rp = row[c];
#pragma unroll
        for (int v = 0; v < 20; ++v) acc[v] += wv * rp[v];
    }
    float* dst = A0 + (size_t)(b * 400 + u * 20) * 256 + t;
#pragma unroll
    for (int v = 0; v < 20; ++v) dst[(size_t)v * 256] = acc[v];
}

// ---------- main: blocks 0..31 = template, 32..9279 = candidate patches ----------
// LDS (bytes), 30784 total -> 5 blocks/CU:
//   h0hi [16p][256c] bf16 swz @0 (8K) | h0lo @8192 (8K)
//   h1hi @16384 (4K) | h1lo @20480 (4K) | h2hi @24576 (2K) | h2lo @26624 (2K)
//   h3 f32 @28672 (2K) | wn @30720
//   overlays: template patchL @0 (16K), meanp @16384 (1K); fallback mean @16384
__global__ __launch_bounds__(256) void main_kernel(
    const float* __restrict__ tf, const float* __restrict__ cand,
    const float* __restrict__ w4, const float* __restrict__ A0,
    float* __restrict__ out, int use_m0)
{
    __shared__ __align__(16) char smem[30784];
    const int OFF_H0HI = 0, OFF_H0LO = 8192;
    const int OFF_H1HI = 16384, OFF_H1LO = 20480;
    const int OFF_H2HI = 24576, OFF_H2LO = 26624;
    const int OFF_H3 = 28672, OFF_WN = 30720;

    int blk = blockIdx.x, t = threadIdx.x;
    int l = t & 63, w = t >> 6;
    bool is_tpl = blk < 32;
    float patch[16];
    int b, r = 0;

    if (!is_tpl) {
        int idx0 = blk - 32;
        int idx = (idx0 & 7) * 1156 + (idx0 >> 3);   // XCD swizzle: 9248 = 8*1156 (bijective)
        b = idx / 289; r = idx % 289;
        int y = r / 17, x = r % 17;
        const float* csrc = cand + (size_t)(b * 256 + t) * 400 + y * 20 + x;
#pragma unroll
        for (int p = 0; p < 16; ++p) patch[p] = csrc[(p >> 2) * 20 + (p & 3)];

        if (use_m0) {
            // fast path: both W0 halves precomputed per pixel
            const float* af = A0 + (size_t)(b * 400 + y * 20 + x) * 512;
            float m0 = 0.f, a0x[16];
#pragma unroll
            for (int p = 0; p < 16; ++p) {
                int po = ((p >> 2) * 20 + (p & 3)) * 512;
                m0 += af[po + t];             // mean-half (coalesced)
                a0x[p] = af[po + 256 + t];    // pixel-half (coalesced)
            }
            m0 *= (1.f / 16.f);
#pragma unroll
            for (int p = 0; p < 16; ++p) {
                float h = lrelu(m0 + a0x[p]);
                unsigned short hi, lo; split_bf(h, hi, lo);
                int byte = p * 512 + ((((t >> 3) ^ (p & 7)) << 4)) + (t & 7) * 2;
                *(unsigned short*)(smem + OFF_H0HI + byte) = hi;
                *(unsigned short*)(smem + OFF_H0LO + byte) = lo;
            }
        } else {
            // fallback: in-block mean matvec (proven round-4 path)
            float s = 0.f;
#pragma unroll
            for (int p = 0; p < 16; ++p) s += patch[p];
            float* mean_ = (float*)(smem + OFF_H1HI);
            mean_[t] = s * (1.f / 16.f);
            __syncthreads();
            float m0 = 0.f;
            for (int c = 0; c < 256; ++c) m0 += g_w0T[c * 512 + t] * mean_[c];
            const float* a0p = A0 + (size_t)(b * 400 + y * 20 + x) * 256 + t;
#pragma unroll
            for (int p = 0; p < 16; ++p) {
                float h = lrelu(m0 + a0p[(size_t)(((p >> 2) * 20 + (p & 3))) * 256]);
                unsigned short hi, lo; split_bf(h, hi, lo);
                int byte = p * 512 + ((((t >> 3) ^ (p & 7)) << 4)) + (t & 7) * 2;
                *(unsigned short*)(smem + OFF_H0HI + byte) = hi;
                *(unsigned short*)(smem + OFF_H0LO + byte) = lo;
            }
        }
    } else {
        b = blk;
        float* meanp = (float*)(smem + OFF_H1HI);
        float (*patchL)[16] = (float(*)[16])(smem + OFF_H0HI);  // overlays h0 (16K)
        const float* src = tf + (size_t)(b * 256 + t) * 16;
        float s = 0.f;
#pragma unroll
        for (int p = 0; p < 16; ++p) {
            float v = src[p];
            patch[p] = v; patchL[t][p] = v; s += v;
        }
        meanp[t] = s * (1.f / 16.f);
        __syncthreads();
        float m0 = 0.f, accp[16];
#pragma unroll
        for (int p = 0; p < 16; ++p) accp[p] = 0.f;
        for (int c = 0; c < 256; ++c) {
            float wm = g_w0T[c * 512 + t];
            float wp = g_w0T[c * 512 + 256 + t];
            m0 += wm * meanp[c];
            const float* pr = patchL[c];
#pragma unroll
            for (int p = 0; p < 16; ++p) accp[p] += wp * pr[p];
        }
        __syncthreads();   // all patchL reads done before h0 overwrites the region
#pragma unroll
        for (int p = 0; p < 16; ++p) {
            float h = lrelu(m0 + accp[p]);
            unsigned short hi, lo; split_bf(h, hi, lo);
            int byte = p * 512 + ((((t >> 3) ^ (p & 7)) << 4)) + (t & 7) * 2;
            *(unsigned short*)(smem + OFF_H0HI + byte) = hi;
            *(unsigned short*)(smem + OFF_H0LO + byte) = lo;
        }
    }
    __syncthreads();

    int p_ = l & 15, q = l >> 4;

    // ---- layer 1: [128x256]x[256x16]; wave w owns M-tiles 2w,2w+1; 3-MFMA hi/lo ----
    {
        f32x4 acc0 = {0.f, 0.f, 0.f, 0.f}, acc1 = {0.f, 0.f, 0.f, 0.f};
        const short8v* A1h = (const short8v*)g_wp1h;
        const short8v* A1l = (const short8v*)g_wp1l;
#pragma unroll
        for (int k0 = 0; k0 < 8; ++k0) {
            int off = p_ * 512 + ((((k0 * 4 + q) ^ (p_ & 7)) << 4));
            short8v bh = *(const short8v*)(smem + OFF_H0HI + off);
            short8v bl = *(const short8v*)(smem + OFF_H0LO + off);
            short8v ah0 = A1h[((2 * w) * 8 + k0) * 64 + l];
            short8v al0 = A1l[((2 * w) * 8 + k0) * 64 + l];
            short8v ah1 = A1h[((2 * w + 1) * 8 + k0) * 64 + l];
            short8v al1 = A1l[((2 * w + 1) * 8 + k0) * 64 + l];
            acc0 = __builtin_amdgcn_mfma_f32_16x16x32_bf16(ah0, bh, acc0, 0, 0, 0);
            acc0 = __builtin_amdgcn_mfma_f32_16x16x32_bf16(ah0, bl, acc0, 0, 0, 0);
            acc0 = __builtin_amdgcn_mfma_f32_16x16x32_bf16(al0, bh, acc0, 0, 0, 0);
            acc1 = __builtin_amdgcn_mfma_f32_16x16x32_bf16(ah1, bh, acc1, 0, 0, 0);
            acc1 = __builtin_amdgcn_mfma_f32_16x16x32_bf16(ah1, bl, acc1, 0, 0, 0);
            acc1 = __builtin_amdgcn_mfma_f32_16x16x32_bf16(al1, bh, acc1, 0, 0, 0);
        }
        int gr0 = 2 * (2 * w) + (q >> 1), gr1 = 2 * (2 * w + 1) + (q >> 1);
        uint2 ph0, pl0, ph1, pl1;
        pack_hilo(acc0, ph0, pl0);
        pack_hilo(acc1, ph1, pl1);
        int e0 = p_ * 256 + ((gr0 ^ (p_ & 7)) << 4) + (q & 1) * 8;
        int e1 = p_ * 256 + ((gr1 ^ (p_ & 7)) << 4) + (q & 1) * 8;
        *(uint2*)(smem + OFF_H1HI + e0) = ph0;
        *(uint2*)(smem + OFF_H1LO + e0) = pl0;
        *(uint2*)(smem + OFF_H1HI + e1) = ph1;
        *(uint2*)(smem + OFF_H1LO + e1) = pl1;
    }
    __syncthreads();

    // ---- layer 2: [64x128]x[128x16]; wave w owns M-tile w ----
    {
        f32x4 acc = {0.f, 0.f, 0.f, 0.f};
        const short8v* A2h = (const short8v*)g_wp2h;
        const short8v* A2l = (const short8v*)g_wp2l;
#pragma unroll
        for (int k0 = 0; k0 < 4; ++k0) {
            int off = p_ * 256 + ((((k0 * 4 + q) ^ (p_ & 7)) << 4));
            short8v bh = *(const short8v*)(smem + OFF_H1HI + off);
            short8v bl = *(const short8v*)(smem + OFF_H1LO + off);
            short8v ah = A2h[(w * 4 + k0) * 64 + l];
            short8v al = A2l[(w * 4 + k0) * 64 + l];
            acc = __builtin_amdgcn_mfma_f32_16x16x32_bf16(ah, bh, acc, 0, 0, 0);
            acc = __builtin_amdgcn_mfma_f32_16x16x32_bf16(ah, bl, acc, 0, 0, 0);
            acc = __builtin_amdgcn_mfma_f32_16x16x32_bf16(al, bh, acc, 0, 0, 0);
        }
        int gr = 2 * w + (q >> 1);
        uint2 ph, pl;
        pack_hilo(acc, ph, pl);
        int e = p_ * 128 + ((gr ^ (p_ & 7)) << 4) + (q & 1) * 8;
        *(uint2*)(smem + OFF_H2HI + e) = ph;
        *(uint2*)(smem + OFF_H2LO + e) = pl;
    }
    __syncthreads();

    // ---- layer 3: [32x64]x[64x16]; waves 0,1; h3 stored fp32 ----
    if (w < 2) {
        f32x4 acc = {0.f, 0.f, 0.f, 0.f};
        const short8v* A3h = (const short8v*)g_wp3h;
        const short8v* A3l = (const short8v*)g_wp3l;
#pragma unroll
        for (int k0 = 0; k0 < 2; ++k0) {
            int off = p_ * 128 + ((((k0 * 4 + q) ^ (p_ & 7)) << 4));
            short8v bh = *(const short8v*)(smem + OFF_H2HI + off);
            short8v bl = *(const short8v*)(smem + OFF_H2LO + off);
            short8v ah = A3h[(w * 2 + k0) * 64 + l];
            short8v al = A3l[(w * 2 + k0) * 64 + l];
            acc = __builtin_amdgcn_mfma_f32_16x16x32_bf16(ah, bh, acc, 0, 0, 0);
            acc = __builtin_amdgcn_mfma_f32_16x16x32_bf16(ah, bl, acc, 0, 0, 0);
            acc = __builtin_amdgcn_mfma_f32_16x16x32_bf16(al, bh, acc, 0, 0, 0);
        }
#pragma unroll
        for (int rg = 0; rg < 4; ++rg) {
            float v = lrelu(acc[rg]);
            int oc = w * 16 + q * 4 + rg;
            *(float*)(smem + OFF_H3 + p_ * 128 + ((oc ^ (p_ & 7)) << 2)) = v;
        }
    }
    __syncthreads();

    // ---- layer 4 + softmax ----
    float* wn = (float*)(smem + OFF_WN);
    if (t < 16) {
        float s = 0.f;
#pragma unroll
        for (int c = 0; c < 32; ++c)
            s += w4[c] * *(const float*)(smem + OFF_H3 + t * 128 + ((c ^ (t & 7)) << 2));
        wn[t] = s;
    }
    __syncthreads();
    if (t == 0) {
        float m = wn[0];
#pragma unroll
        for (int p = 1; p < 16; ++p) m = fmaxf(m, wn[p]);
        float e[16], sum = 0.f;
#pragma unroll
        for (int p = 0; p < 16; ++p) { e[p] = __expf(wn[p] - m); sum += e[p]; }
        float inv = 1.f / sum;
#pragma unroll
        for (int p = 0; p < 16; ++p) wn[p] = e[p] * inv;
    }
    __syncthreads();

    // ---- weighted pooling + store ----
    float accv = 0.f;
#pragma unroll
    for (int p = 0; p < 16; ++p) accv += patch[p] * wn[p];
    if (is_tpl) {
        out[b * 272 + t] = accv;
        if (t < 16) out[b * 272 + 256 + t] = wn[t];
    } else {
        out[8704 + (size_t)(b * 256 + t) * 289 + r] = accv;
    }
}

// ---------- launch ----------
extern "C" void kernel_launch(void* const* d_in, const int* in_sizes, int n_in,
                              void* d_out, int out_size, void* d_ws, size_t ws_size,
                              hipStream_t stream)
{
    const float* tf = (const float*)d_in[0];
    const float* cf = (const float*)d_in[1];
    const float* w0 = (const float*)d_in[2];
    const float* w1 = (const float*)d_in[3];
    const float* w2 = (const float*)d_in[4];
    const float* w3 = (const float*)d_in[5];
    const float* w4 = (const float*)d_in[6];
    float* out = (float*)d_out;
    float* A0 = (float*)d_ws;

    const size_t WIDE_BYTES = (size_t)32 * 400 * 512 * 4;   // 26.2 MB
    int wide = (ws_size >= WIDE_BYTES) ? 1 : 0;

    prep_kernel<<<680, 256, 0, stream>>>(w0, w1, w2, w3);
    if (wide) a0_wide_kernel<<<32 * 20, 512, 0, stream>>>(cf, A0);
    else      a0_narrow_kernel<<<32 * 20, 256, 0, stream>>>(cf, A0);
    main_kernel<<<32 + 32 * 289, 256, 0, stream>>>(tf, cf, w4, A0, out, wide);
}